// Round 1
// baseline (711.750 us; speedup 1.0000x reference)
//
#include <hip/hip_runtime.h>
#include <math.h>

// Problem constants (mirroring the reference)
#define IMG_H 480
#define IMG_W 640
#define DU    4
#define SUB_H 120          // IMG_H / DU
#define SUB_W 160          // IMG_W / DU
#define NSEM  16
#define NCH_IN 20          // 4 + NSEM input channels
#define VR    100
#define ZBINS 80           // MAX_VOX - MIN_VOX = 72 - (-8)
#define MIN_MAPPED 13      // 25/5 - (-8)
#define MAX_MAPPED 25      // int(89/5) - (-8)
#define NOUT  18           // 2 + NSEM
#define NCELL (VR * VR)

// One thread per (frame, subsampled pixel). Scatter-add into the per-frame
// 18-channel 100x100 accumulator:
//   d_out ch1      <- explored count (all valid z)
//   d_out ch2..17  <- sem sums (all valid z)
//   d_ws  (agent)  <- agent-height count (z in [13,25)) -- raw, pre-dilation
__global__ void scatter_kernel(const float* __restrict__ obs,
                               float* __restrict__ out,
                               float* __restrict__ agent,
                               int nframes, float f_pix) {
    const int npix = SUB_H * SUB_W;
    int tid = blockIdx.x * blockDim.x + threadIdx.x;
    if (tid >= nframes * npix) return;
    int f = tid / npix;
    int p = tid - f * npix;
    int v = p / SUB_W;
    int u = p - v * SUB_W;

    const float* frame = obs + (size_t)f * NCH_IN * IMG_H * IMG_W;
    size_t pix_off = (size_t)(v * DU) * IMG_W + (size_t)(u * DU);

    float depth = frame[(size_t)3 * IMG_H * IMG_W + pix_off];
    if (!(depth > 20.0f && depth < 500.0f)) return;

    // Match the np reference's fp32 op order exactly.
    float uu = (float)(u * DU);
    float vv = (float)(v * DU);
    float X  = (uu - 320.0f) * depth / f_pix;
    float Zh = 88.0f + (240.0f - vv) * depth / f_pix;

    // np.round is half-to-even; rintf honors the default round-nearest-even.
    int xb = (int)rintf(X / 5.0f + 50.0f);
    int yb = (int)rintf(depth / 5.0f);
    int zb = (int)rintf(Zh / 5.0f) + 8;     // - MIN_VOX (= -8)

    if (xb < 0 || xb >= VR || yb < 0 || yb >= VR || zb < 0 || zb >= ZBINS) return;

    int cell = yb * VR + xb;
    float* outf = out + (size_t)f * NOUT * NCELL;

    atomicAdd(&outf[1 * NCELL + cell], 1.0f);          // explored count
    if (zb >= MIN_MAPPED && zb < MAX_MAPPED)
        atomicAdd(&agent[(size_t)f * NCELL + cell], 1.0f);

    #pragma unroll
    for (int c = 0; c < NSEM; ++c) {
        float s = frame[(size_t)(4 + c) * IMG_H * IMG_W + pix_off];
        atomicAdd(&outf[(2 + c) * NCELL + cell], s);
    }
}

// One thread per (frame, cell). Channel 0: 3x3 max-dilate of raw agent count
// then clip (clip∘max == max∘clip, both values >= 0). Channels 1..17: clip
// in place.
__global__ void finalize_kernel(float* __restrict__ out,
                                const float* __restrict__ agent,
                                int nframes) {
    int tid = blockIdx.x * blockDim.x + threadIdx.x;
    if (tid >= nframes * NCELL) return;
    int f = tid / NCELL;
    int p = tid - f * NCELL;
    int y = p / VR;
    int x = p - y * VR;

    const float* ag = agent + (size_t)f * NCELL;
    float m = 0.0f;
    #pragma unroll
    for (int dy = -1; dy <= 1; ++dy) {
        int yy = y + dy;
        if (yy < 0 || yy >= VR) continue;
        #pragma unroll
        for (int dx = -1; dx <= 1; ++dx) {
            int xx = x + dx;
            if (xx < 0 || xx >= VR) continue;
            m = fmaxf(m, ag[yy * VR + xx]);
        }
    }

    float* outf = out + (size_t)f * NOUT * NCELL;
    outf[p] = fminf(m, 1.0f);                              // obstacle (dilated)

    float e = outf[1 * NCELL + p];
    outf[1 * NCELL + p] = fminf(fmaxf(e, 0.0f), 1.0f);     // explored

    #pragma unroll
    for (int c = 0; c < NSEM; ++c) {
        float s = outf[(2 + c) * NCELL + p];
        outf[(2 + c) * NCELL + p] = fminf(fmaxf(s / 5.0f, 0.0f), 1.0f);
    }
}

extern "C" void kernel_launch(void* const* d_in, const int* in_sizes, int n_in,
                              void* d_out, int out_size, void* d_ws, size_t ws_size,
                              hipStream_t stream) {
    const float* obs = (const float*)d_in[0];
    float* out = (float*)d_out;
    float* agent = (float*)d_ws;

    int nframes = in_sizes[0] / (NCH_IN * IMG_H * IMG_W);   // B*T = 16

    // F_PIX = W/2 / tan(deg2rad(HFOV/2)), computed in double like numpy,
    // then cast to fp32 (numpy weak-scalar promotion does the same).
    float f_pix = (float)(IMG_W / 2.0 / tan((79.0 / 2.0) * M_PI / 180.0));

    // Accumulators must start at zero (harness poisons d_out/d_ws with 0xAA).
    hipMemsetAsync(d_out, 0, (size_t)nframes * NOUT * NCELL * sizeof(float), stream);
    hipMemsetAsync(d_ws, 0, (size_t)nframes * NCELL * sizeof(float), stream);

    int npix_total = nframes * SUB_H * SUB_W;
    scatter_kernel<<<(npix_total + 255) / 256, 256, 0, stream>>>(
        obs, out, agent, nframes, f_pix);

    int ncell_total = nframes * NCELL;
    finalize_kernel<<<(ncell_total + 255) / 256, 256, 0, stream>>>(
        out, agent, nframes);
}

// Round 2
// 605.231 us; speedup vs baseline: 1.1760x; 1.1760x over previous
//
#include <hip/hip_runtime.h>
#include <math.h>

// Problem constants (mirroring the reference)
#define IMG_H 480
#define IMG_W 640
#define DU    4
#define SUB_H 120          // IMG_H / DU
#define SUB_W 160          // IMG_W / DU
#define NPIX  (SUB_H * SUB_W)   // 19200
#define NSEM  16
#define NCH_IN 20          // 4 + NSEM input channels
#define VR    100
#define ZBINS 80           // MAX_VOX - MIN_VOX = 72 - (-8)
#define MIN_MAPPED 13      // 25/5 - (-8)
#define MAX_MAPPED 25      // int(89/5) - (-8)
#define NOUT  18           // 2 + NSEM
#define NCELL (VR * VR)    // 10000
#define NJOBS 18           // per frame: job0=agent/obstacle, job1=explored, job2..17=sem
#define BLOCK 512

// One block per (frame, job). The whole frame's 100x100 cell accumulator for
// one channel lives in LDS (40 KB) -> zero global atomics. Each block redoes
// the (cheap) binning math for its frame; depth reads are L2-absorbed across
// the 18 jobs of a frame. Job 0 accumulates the agent-height count and does
// the 3x3 dilation straight out of LDS. Jobs 1..17 clip inline on store.
__global__ __launch_bounds__(BLOCK, 2)
void ego_map_kernel(const float* __restrict__ obs,
                    float* __restrict__ out,
                    float f_pix) {
    __shared__ float acc[NCELL];

    const int f = blockIdx.x / NJOBS;
    const int j = blockIdx.x - f * NJOBS;
    const int tid = threadIdx.x;

    for (int c = tid; c < NCELL; c += BLOCK) acc[c] = 0.0f;
    __syncthreads();

    const float* frame = obs + (size_t)f * NCH_IN * IMG_H * IMG_W;
    const float* depth_ch = frame + (size_t)3 * IMG_H * IMG_W;
    const float* sem_ch   = (j >= 2) ? frame + (size_t)(4 + (j - 2)) * IMG_H * IMG_W
                                     : depth_ch;  // unused for j<2

    for (int p = tid; p < NPIX; p += BLOCK) {
        int v = p / SUB_W;
        int u = p - v * SUB_W;
        size_t pix_off = (size_t)(v * DU) * IMG_W + (size_t)(u * DU);

        float depth = depth_ch[pix_off];
        if (!(depth > 20.0f && depth < 500.0f)) continue;

        // Match the np reference's fp32 op order exactly.
        float uu = (float)(u * DU);
        float vv = (float)(v * DU);
        float X  = (uu - 320.0f) * depth / f_pix;
        float Zh = 88.0f + (240.0f - vv) * depth / f_pix;

        // np.round is half-to-even; rintf honors round-nearest-even.
        int xb = (int)rintf(X / 5.0f + 50.0f);
        int yb = (int)rintf(depth / 5.0f);
        int zb = (int)rintf(Zh / 5.0f) + 8;   // - MIN_VOX (= -8)

        if (xb < 0 || xb >= VR || yb < 0 || yb >= VR || zb < 0 || zb >= ZBINS)
            continue;

        int cell = yb * VR + xb;
        if (j == 0) {
            if (zb >= MIN_MAPPED && zb < MAX_MAPPED)
                atomicAdd(&acc[cell], 1.0f);           // ds_add_f32
        } else if (j == 1) {
            atomicAdd(&acc[cell], 1.0f);
        } else {
            atomicAdd(&acc[cell], sem_ch[pix_off]);
        }
    }
    __syncthreads();

    float* outf = out + (size_t)f * NOUT * NCELL;

    if (j == 0) {
        // 3x3 max-dilate from LDS, then clip (max/clip commute, values >= 0).
        for (int c = tid; c < NCELL; c += BLOCK) {
            int y = c / VR;
            int x = c - y * VR;
            float m = 0.0f;
            int y0 = (y > 0) ? y - 1 : 0, y1 = (y < VR - 1) ? y + 1 : VR - 1;
            int x0 = (x > 0) ? x - 1 : 0, x1 = (x < VR - 1) ? x + 1 : VR - 1;
            for (int yy = y0; yy <= y1; ++yy)
                for (int xx = x0; xx <= x1; ++xx)
                    m = fmaxf(m, acc[yy * VR + xx]);
            outf[c] = fminf(m, 1.0f);                   // obstacle
        }
    } else if (j == 1) {
        for (int c = tid; c < NCELL; c += BLOCK)
            outf[NCELL + c] = fminf(fmaxf(acc[c], 0.0f), 1.0f);   // explored
    } else {
        float* oc = outf + (size_t)j * NCELL;           // ch 2..17
        for (int c = tid; c < NCELL; c += BLOCK)
            oc[c] = fminf(fmaxf(acc[c] / 5.0f, 0.0f), 1.0f);      // sem
    }
}

extern "C" void kernel_launch(void* const* d_in, const int* in_sizes, int n_in,
                              void* d_out, int out_size, void* d_ws, size_t ws_size,
                              hipStream_t stream) {
    const float* obs = (const float*)d_in[0];
    float* out = (float*)d_out;

    int nframes = in_sizes[0] / (NCH_IN * IMG_H * IMG_W);   // B*T = 16

    // F_PIX = W/2 / tan(deg2rad(HFOV/2)) in double like numpy, then fp32.
    float f_pix = (float)(IMG_W / 2.0 / tan((79.0 / 2.0) * M_PI / 180.0));

    ego_map_kernel<<<nframes * NJOBS, BLOCK, 0, stream>>>(obs, out, f_pix);
}

// Round 3
// 595.158 us; speedup vs baseline: 1.1959x; 1.0169x over previous
//
#include <hip/hip_runtime.h>
#include <math.h>

// Problem constants (mirroring the reference)
#define IMG_H 480
#define IMG_W 640
#define DU    4
#define SUB_H 120          // IMG_H / DU
#define SUB_W 160          // IMG_W / DU
#define NPIX  (SUB_H * SUB_W)   // 19200
#define NSEM  16
#define NCH_IN 20          // 4 + NSEM input channels
#define VR    100
#define ZBINS 80           // MAX_VOX - MIN_VOX = 72 - (-8)
#define MIN_MAPPED 13      // 25/5 - (-8)
#define MAX_MAPPED 25      // int(89/5) - (-8)
#define NOUT  18           // 2 + NSEM
#define NCELL (VR * VR)    // 10000
#define NJOBS 17           // job0 = agent+explored (depth only), job1..16 = sem ch
#define BLOCK 1024

// One block per (frame, job). Per-channel 100x100 accumulators live in LDS
// (40 KB each) -> zero global atomics. Job 0 builds BOTH the agent-height
// grid (-> 3x3 dilated obstacle ch0) and the explored grid (ch1) from the
// depth channel alone. Jobs 1..16 build one sem channel each. 1024 threads
// per block halves the sequential pixel-loop depth vs 512 and doubles
// resident waves (16/block) for latency hiding at ~1 block/CU.
__global__ __launch_bounds__(BLOCK, 1)
void ego_map_kernel(const float* __restrict__ obs,
                    float* __restrict__ out,
                    float f_pix) {
    __shared__ float acc[NCELL];        // agent grid (job0) or sem grid (job>=1)
    __shared__ float acc2[NCELL];       // explored grid (job0 only)

    const int f = blockIdx.x / NJOBS;
    const int j = blockIdx.x - f * NJOBS;
    const int tid = threadIdx.x;

    for (int c = tid; c < NCELL; c += BLOCK) acc[c] = 0.0f;
    if (j == 0)
        for (int c = tid; c < NCELL; c += BLOCK) acc2[c] = 0.0f;
    __syncthreads();

    const float* frame = obs + (size_t)f * NCH_IN * IMG_H * IMG_W;
    const float* depth_ch = frame + (size_t)3 * IMG_H * IMG_W;
    const float* sem_ch   = (j >= 1) ? frame + (size_t)(4 + (j - 1)) * IMG_H * IMG_W
                                     : depth_ch;  // unused for j==0

    for (int p = tid; p < NPIX; p += BLOCK) {
        int v = p / SUB_W;
        int u = p - v * SUB_W;
        size_t pix_off = (size_t)(v * DU) * IMG_W + (size_t)(u * DU);

        float depth = depth_ch[pix_off];
        if (!(depth > 20.0f && depth < 500.0f)) continue;

        // Match the np reference's fp32 op order exactly (true divisions --
        // no reciprocal rewrite, binning must be bit-exact).
        float uu = (float)(u * DU);
        float vv = (float)(v * DU);
        float X  = (uu - 320.0f) * depth / f_pix;
        float Zh = 88.0f + (240.0f - vv) * depth / f_pix;

        // np.round is half-to-even; rintf honors round-nearest-even.
        int xb = (int)rintf(X / 5.0f + 50.0f);
        int yb = (int)rintf(depth / 5.0f);
        int zb = (int)rintf(Zh / 5.0f) + 8;   // - MIN_VOX (= -8)

        if (xb < 0 || xb >= VR || yb < 0 || yb >= VR || zb < 0 || zb >= ZBINS)
            continue;

        int cell = yb * VR + xb;
        if (j == 0) {
            if (zb >= MIN_MAPPED && zb < MAX_MAPPED)
                atomicAdd(&acc[cell], 1.0f);       // agent-height count
            atomicAdd(&acc2[cell], 1.0f);          // explored count
        } else {
            atomicAdd(&acc[cell], sem_ch[pix_off]);
        }
    }
    __syncthreads();

    float* outf = out + (size_t)f * NOUT * NCELL;

    if (j == 0) {
        for (int c = tid; c < NCELL; c += BLOCK) {
            int y = c / VR;
            int x = c - y * VR;
            // 3x3 max-dilate from LDS, then clip (max/clip commute, >= 0).
            float m = 0.0f;
            int y0 = (y > 0) ? y - 1 : 0, y1 = (y < VR - 1) ? y + 1 : VR - 1;
            int x0 = (x > 0) ? x - 1 : 0, x1 = (x < VR - 1) ? x + 1 : VR - 1;
            for (int yy = y0; yy <= y1; ++yy)
                for (int xx = x0; xx <= x1; ++xx)
                    m = fmaxf(m, acc[yy * VR + xx]);
            outf[c] = fminf(m, 1.0f);                              // obstacle
            outf[NCELL + c] = fminf(fmaxf(acc2[c], 0.0f), 1.0f);   // explored
        }
    } else {
        float* oc = outf + (size_t)(1 + j) * NCELL;    // sem ch 2..17
        for (int c = tid; c < NCELL; c += BLOCK)
            oc[c] = fminf(fmaxf(acc[c] / 5.0f, 0.0f), 1.0f);
    }
}

extern "C" void kernel_launch(void* const* d_in, const int* in_sizes, int n_in,
                              void* d_out, int out_size, void* d_ws, size_t ws_size,
                              hipStream_t stream) {
    const float* obs = (const float*)d_in[0];
    float* out = (float*)d_out;

    int nframes = in_sizes[0] / (NCH_IN * IMG_H * IMG_W);   // B*T = 16

    // F_PIX = W/2 / tan(deg2rad(HFOV/2)) in double like numpy, then fp32.
    float f_pix = (float)(IMG_W / 2.0 / tan((79.0 / 2.0) * M_PI / 180.0));

    ego_map_kernel<<<nframes * NJOBS, BLOCK, 0, stream>>>(obs, out, f_pix);
}